// Round 10
// baseline (387.597 us; speedup 1.0000x reference)
//
#include <hip/hip_runtime.h>
#include <hip/hip_bf16.h>
#include <cstddef>

#define N_NODES 50000
#define N_EDGES 800000
#define HDIM    128
#define TME     64
#define TMN     64

// padded LDS row strides (bytes)
#define RB128   272

// scan geometry
#define SCHUNK  512
#define SNBLK   ((N_NODES + SCHUNK - 1) / SCHUNK)   // 98

typedef __attribute__((ext_vector_type(4)))  float f32x4;
typedef __attribute__((ext_vector_type(16))) float f32x16;
typedef __attribute__((ext_vector_type(8)))  short bf16x8;

// pack: 7 segments x 16384 bf16. Segments 2 (eW1) and 3 (cW0) are in
// 32x32x16 A-frag layout (consumed by the edge kernel); the rest are in
// 16x16x32 layout (consumed by h0/node kernels).
#define OFF_EW0T 0
#define OFF_EW0B 16384
#define OFF_EW1  32768
#define OFF_CW0  49152
#define OFF_NW0T 65536
#define OFF_NW0B 81920
#define OFF_NW1  98304
#define PACK_ELEMS 114688

__device__ __forceinline__ float silu(float x) {
    float e = __expf(-x);
    return __fdividef(x, 1.0f + e);
}
__device__ __forceinline__ unsigned short f2bf(float f) {
    union { __hip_bfloat16 h; unsigned short u; } cv;
    cv.h = __float2bfloat16(f);
    return cv.u;
}
__device__ __forceinline__ unsigned int f2bf2(float a, float b) {
    union { __hip_bfloat162 h; unsigned int u; } cv;
    cv.h = __float22bfloat162_rn(float2{a, b});
    return cv.u;
}
__device__ __forceinline__ float bf2f(unsigned short u) {
    return __uint_as_float(((unsigned int)u) << 16);
}
__device__ __forceinline__ float bflo(unsigned int u) {
    return __uint_as_float(u << 16);
}
__device__ __forceinline__ float bfhi(unsigned int u) {
    return __uint_as_float(u & 0xffff0000u);
}

// ---------------- weight pack (mixed layouts) ----------------
__global__ void pack_weights(const float* __restrict__ eW0, const float* __restrict__ eW1,
                             const float* __restrict__ cW0, const float* __restrict__ nW0,
                             const float* __restrict__ nW1, unsigned short* __restrict__ pack)
{
    int g = blockIdx.x * blockDim.x + threadIdx.x;   // 0 .. 14335
    int fg = g >> 6;
    int lane = g & 63;
    int s = fg >> 5;          // segment 0..6
    int f = fg & 31;
    const float* W; int rowoff = 0;
    switch (s) {
        case 0: W = eW0; break;
        case 1: W = eW0; rowoff = 128; break;
        case 2: W = eW1; break;
        case 3: W = cW0; break;
        case 4: W = nW0; break;
        case 5: W = nW0; rowoff = 128; break;
        default: W = nW1; break;
    }
    int base = s * 16384;
    int col, kbase;
    if (s == 2 || s == 3) {
        // 32x32x16 A-frag: f = ct*8 + ks; lane holds W[ks*16 + (lane>>5)*8 + q][ct*32 + (lane&31)]
        int ct = f >> 3, ks = f & 7;
        col = ct * 32 + (lane & 31);
        kbase = rowoff + ks * 16 + ((lane >> 5) << 3);
    } else {
        // 16x16x32 frag: f = cb*4 + ks; lane holds W[ks*32 + (lane>>4)*8 + j][cb*16 + (lane&15)]
        int cb = f >> 2, ks = f & 3;
        col = cb * 16 + (lane & 15);
        kbase = rowoff + ks * 32 + ((lane >> 4) << 3);
    }
#pragma unroll
    for (int j = 0; j < 8; ++j)
        pack[(size_t)base + ((size_t)(f * 64 + lane) * 8 + j)] =
            f2bf(W[(size_t)(kbase + j) * HDIM + col]);
}

// ---------------- multi-block scan over cnt[N] ----------------
__global__ __launch_bounds__(256)
void scanA_kernel(const int* __restrict__ cnt, int* __restrict__ bsum) {
    __shared__ int part[256];
    const int b = blockIdx.x, t = threadIdx.x;
    int i0 = b * SCHUNK + t * 2;
    int s = 0;
    if (i0 < N_NODES)     s += cnt[i0];
    if (i0 + 1 < N_NODES) s += cnt[i0 + 1];
    part[t] = s;
    __syncthreads();
    for (int off = 128; off > 0; off >>= 1) {
        if (t < off) part[t] += part[t + off];
        __syncthreads();
    }
    if (t == 0) bsum[b] = part[0];
}

__global__ __launch_bounds__(128)
void scanB_kernel(const int* __restrict__ bsum, int* __restrict__ boff,
                  int* __restrict__ row_start) {
    __shared__ int part[128];
    const int t = threadIdx.x;
    int s = (t < SNBLK) ? bsum[t] : 0;
    part[t] = s;
    __syncthreads();
    for (int off = 1; off < 128; off <<= 1) {
        int tmp = (t >= off) ? part[t - off] : 0;
        __syncthreads();
        part[t] += tmp;
        __syncthreads();
    }
    boff[t] = part[t] - s;
    if (t == 127) row_start[N_NODES] = part[127];
}

__global__ __launch_bounds__(256)
void scanC_kernel(const int* __restrict__ cnt, const int* __restrict__ boff,
                  int* __restrict__ row_start, int* __restrict__ cursor) {
    __shared__ int part[256];
    const int b = blockIdx.x, t = threadIdx.x;
    int i0 = b * SCHUNK + t * 2;
    int c0 = (i0 < N_NODES) ? cnt[i0] : 0;
    int c1 = (i0 + 1 < N_NODES) ? cnt[i0 + 1] : 0;
    int s = c0 + c1;
    part[t] = s;
    __syncthreads();
    for (int off = 1; off < 256; off <<= 1) {
        int tmp = (t >= off) ? part[t - off] : 0;
        __syncthreads();
        part[t] += tmp;
        __syncthreads();
    }
    int base = boff[b] + part[t] - s;
    if (i0 < N_NODES)     { row_start[i0] = base;          cursor[i0] = base; }
    if (i0 + 1 < N_NODES) { row_start[i0 + 1] = base + c0; cursor[i0 + 1] = base + c0; }
}

__global__ void scatter_kernel(const int* __restrict__ eidx, int* __restrict__ cursor,
                               int2* __restrict__ rc) {
    int e = (blockIdx.x * blockDim.x + threadIdx.x) * 4;
    if (e + 3 < N_EDGES) {
        int4 r4 = *(const int4*)(eidx + e);
        int4 c4 = *(const int4*)(eidx + N_EDGES + e);
        int p;
        p = atomicAdd(&cursor[r4.x], 1); rc[p] = int2{r4.x, c4.x};
        p = atomicAdd(&cursor[r4.y], 1); rc[p] = int2{r4.y, c4.y};
        p = atomicAdd(&cursor[r4.z], 1); rc[p] = int2{r4.z, c4.z};
        p = atomicAdd(&cursor[r4.w], 1); rc[p] = int2{r4.w, c4.w};
    } else {
        for (int i = e; i < N_EDGES; ++i) {
            int r = eidx[i], c = eidx[N_EDGES + i];
            int p = atomicAdd(&cursor[r], 1);
            rc[p] = int2{r, c};
        }
    }
}

// ---------------- 16x16x32 swapped-operand GEMM (h0/node) ----------------
template<int KS, int ROWB>
__device__ __forceinline__ void gemm_layer_T(const unsigned short* __restrict__ Wseg,
                                             const char* __restrict__ Xs,
                                             int lane, int cb, f32x4 acc[4])
{
    const bf16x8* aptr = (const bf16x8*)Wseg + (size_t)(cb * KS) * 64 + lane;
#pragma unroll
    for (int ks = 0; ks < KS; ++ks) {
        bf16x8 a = aptr[(size_t)ks * 64];
#pragma unroll
        for (int eb = 0; eb < 4; ++eb) {
            int row = eb * 16 + (lane & 15);
            bf16x8 b = *(const bf16x8*)(Xs + row * ROWB + ks * 64 + ((lane >> 4) << 4));
            acc[eb] = __builtin_amdgcn_mfma_f32_16x16x32_bf16(a, b, acc[eb], 0, 0, 0);
        }
    }
}

// ---------------- 32x32x16 split-K dual-chain GEMM (edge) ----------------
// Out^T = W^T @ X^T. Wave (cbw, ebk): edges ebk*32+(lane&31), feats cbw*32..+31.
// Two independent 4-MFMA chains over K halves, merged at the end.
template<int ROWB>
__device__ __forceinline__ void gemm32(const unsigned short* __restrict__ Wseg,
                                       const char* __restrict__ Xs,
                                       int lane, int cbw, int ebk, f32x16& acc)
{
    const bf16x8* aptr = (const bf16x8*)Wseg + (size_t)(cbw * 8) * 64 + lane;
    const char* xrow = Xs + (ebk * 32 + (lane & 31)) * ROWB + ((lane >> 5) << 4);
    f32x16 acc1;
#pragma unroll
    for (int i = 0; i < 16; ++i) acc1[i] = 0.f;
#pragma unroll
    for (int ks = 0; ks < 4; ++ks) {
        bf16x8 a0 = aptr[(size_t)ks * 64];
        bf16x8 b0 = *(const bf16x8*)(xrow + ks * 32);
        bf16x8 a1 = aptr[(size_t)(ks + 4) * 64];
        bf16x8 b1 = *(const bf16x8*)(xrow + (ks + 4) * 32);
        acc  = __builtin_amdgcn_mfma_f32_32x32x16_bf16(a0, b0, acc,  0, 0, 0);
        acc1 = __builtin_amdgcn_mfma_f32_32x32x16_bf16(a1, b1, acc1, 0, 0, 0);
    }
#pragma unroll
    for (int i = 0; i < 16; ++i) acc[i] += acc1[i];
}

// feats for 32x32 C layout (m74): f = cbw*32 + rq*8 + (lane>>5)*4 + {0..3}
#define F0(rq) (cbw * 32 + (rq) * 8 + ((lane >> 5) << 2))

// ---------------- H0 precompute: H0r, H0c, Hn0 (+ fused histogram) ----------------
__global__ __launch_bounds__(512, 2)
void h0_kernel(const float* __restrict__ h, const float* __restrict__ eb0,
               const float* __restrict__ nb0,
               const unsigned short* __restrict__ pack,
               const int* __restrict__ eidx, int* __restrict__ cnt,
               unsigned short* __restrict__ H0r, unsigned short* __restrict__ H0c,
               unsigned short* __restrict__ Hn0)
{
    __shared__ __align__(16) char Xs[TMN * RB128];
    const int tid = threadIdx.x, lane = tid & 63, cb = tid >> 6;
    const int n0 = blockIdx.x * TMN;

    {
        int e = blockIdx.x * 1024 + tid * 2;
        if (e + 1 < N_EDGES) {
            int2 rr = *(const int2*)(eidx + e);
            atomicAdd(&cnt[rr.x], 1);
            atomicAdd(&cnt[rr.y], 1);
        } else if (e < N_EDGES) {
            atomicAdd(&cnt[eidx[e]], 1);
        }
    }

    {
        const int nl = tid >> 3, sub = tid & 7, n = n0 + nl;
        if (n < N_NODES) {
            const float4* h4 = (const float4*)(h + (size_t)n * HDIM);
#pragma unroll
            for (int q = 0; q < 4; ++q) {
                float4 f = h4[sub + q * 8];
                uint2 u; u.x = f2bf2(f.x, f.y); u.y = f2bf2(f.z, f.w);
                *(uint2*)(Xs + nl * RB128 + (sub + q * 8) * 8) = u;
            }
        } else {
            uint2 z{0, 0};
#pragma unroll
            for (int q = 0; q < 4; ++q)
                *(uint2*)(Xs + nl * RB128 + (sub + q * 8) * 8) = z;
        }
    }
    __syncthreads();

    const int j0 = cb * 16 + ((lane >> 4) << 2);
    f32x4 acc[4];
    // GEMM 1: H0r = h @ eW0T + eb0
    {
        float4 b0 = *(const float4*)(eb0 + j0);
#pragma unroll
        for (int eb = 0; eb < 4; ++eb) acc[eb] = f32x4{b0.x, b0.y, b0.z, b0.w};
        gemm_layer_T<4, RB128>(pack + OFF_EW0T, Xs, lane, cb, acc);
#pragma unroll
        for (int eb = 0; eb < 4; ++eb) {
            int n = n0 + eb * 16 + (lane & 15);
            if (n < N_NODES) {
                uint2 u; u.x = f2bf2(acc[eb][0], acc[eb][1]); u.y = f2bf2(acc[eb][2], acc[eb][3]);
                *(uint2*)(H0r + (size_t)n * HDIM + j0) = u;
            }
        }
    }
    // GEMM 2: H0c = h @ eW0B
    {
#pragma unroll
        for (int eb = 0; eb < 4; ++eb) acc[eb] = f32x4{0.f, 0.f, 0.f, 0.f};
        gemm_layer_T<4, RB128>(pack + OFF_EW0B, Xs, lane, cb, acc);
#pragma unroll
        for (int eb = 0; eb < 4; ++eb) {
            int n = n0 + eb * 16 + (lane & 15);
            if (n < N_NODES) {
                uint2 u; u.x = f2bf2(acc[eb][0], acc[eb][1]); u.y = f2bf2(acc[eb][2], acc[eb][3]);
                *(uint2*)(H0c + (size_t)n * HDIM + j0) = u;
            }
        }
    }
    // GEMM 3: Hn0 = h @ nW0T + nb0
    {
        float4 b0 = *(const float4*)(nb0 + j0);
#pragma unroll
        for (int eb = 0; eb < 4; ++eb) acc[eb] = f32x4{b0.x, b0.y, b0.z, b0.w};
        gemm_layer_T<4, RB128>(pack + OFF_NW0T, Xs, lane, cb, acc);
#pragma unroll
        for (int eb = 0; eb < 4; ++eb) {
            int n = n0 + eb * 16 + (lane & 15);
            if (n < N_NODES) {
                uint2 u; u.x = f2bf2(acc[eb][0], acc[eb][1]); u.y = f2bf2(acc[eb][2], acc[eb][3]);
                *(uint2*)(Hn0 + (size_t)n * HDIM + j0) = u;
            }
        }
    }
}

// ---------------- edge kernel (sorted order, XCD-chunked, 32x32 split-K) ----------------
__global__ __launch_bounds__(512, 4)
void egnn_edge_kernel(const unsigned short* __restrict__ H0r,
                      const unsigned short* __restrict__ H0c,
                      const float* __restrict__ pos,
                      const int2*  __restrict__ rc,
                      const float* __restrict__ w256,
                      const float* __restrict__ eb1, const float* __restrict__ cb0,
                      const float* __restrict__ cW1,
                      const unsigned short* __restrict__ pack,
                      float* __restrict__ m_i,
                      float* __restrict__ pos_upd)
{
    __shared__ __align__(16) char Ya[TME * RB128];
    __shared__ __align__(16) char Yb[TME * RB128];
    __shared__ float pw[4][TME];
    __shared__ float rad_s[TME];
    __shared__ float dif_s[TME][3];
    __shared__ float cu_s[TME][4];
    __shared__ int   rowb_s[TME];

    const int tid = threadIdx.x, lane = tid & 63, wv = tid >> 6;
    const int cbw = wv & 3, ebk = wv >> 2;

    // bijective XCD-chunked block swizzle
    int lb;
    {
        const int nwg = gridDim.x;
        const int q = nwg >> 3, r = nwg & 7;
        const int xcd = blockIdx.x & 7, idx = blockIdx.x >> 3;
        lb = (xcd < r) ? (xcd * (q + 1) + idx) : (r * (q + 1) + (xcd - r) * q + idx);
    }
    const int e0 = lb * TME;

    // ---- phase 0: gather H0r[row]+H0c[col], radial term, SiLU -> Ya ----
    {
        const int el = tid >> 3, sub = tid & 7, idx = e0 + el;
        const int2 rcv = rc[idx];
        const int r = rcv.x, c = rcv.y;
        float dx = pos[(size_t)r * 3 + 0] - pos[(size_t)c * 3 + 0];
        float dy = pos[(size_t)r * 3 + 1] - pos[(size_t)c * 3 + 1];
        float dz = pos[(size_t)r * 3 + 2] - pos[(size_t)c * 3 + 2];
        float rad = dx * dx + dy * dy + dz * dz;
        if (sub == 0) {
            rad_s[el] = rad;
            dif_s[el][0] = dx; dif_s[el][1] = dy; dif_s[el][2] = dz;
            rowb_s[el] = r;
        }
        const bf16x8* ar = (const bf16x8*)(H0r + (size_t)r * HDIM + sub * 16);
        const bf16x8* ac = (const bf16x8*)(H0c + (size_t)c * HDIM + sub * 16);
        bf16x8 a0 = ar[0], a1 = ar[1];
        bf16x8 c0 = ac[0], c1 = ac[1];
        const float4* wp = (const float4*)(w256 + sub * 16);
        float4 w4[4] = { wp[0], wp[1], wp[2], wp[3] };
        const float* wf = (const float*)w4;
        float v[16];
#pragma unroll
        for (int i = 0; i < 8; ++i) v[i]     = bf2f((unsigned short)a0[i]) + bf2f((unsigned short)c0[i]);
#pragma unroll
        for (int i = 0; i < 8; ++i) v[8 + i] = bf2f((unsigned short)a1[i]) + bf2f((unsigned short)c1[i]);
#pragma unroll
        for (int i = 0; i < 16; ++i) v[i] = silu(fmaf(rad, wf[i], v[i]));
#pragma unroll
        for (int c4 = 0; c4 < 4; ++c4) {
            uint2 u;
            u.x = f2bf2(v[c4 * 4 + 0], v[c4 * 4 + 1]);
            u.y = f2bf2(v[c4 * 4 + 2], v[c4 * 4 + 3]);
            *(uint2*)(Ya + el * RB128 + sub * 32 + c4 * 8) = u;
        }
    }
    __syncthreads();

    const int e_loc = ebk * 32 + (lane & 31);
    f32x16 acc;

    // ---- phase 1: m_ij = silu(Ya @ eW1 + eb1) -> Yb ----
    {
#pragma unroll
        for (int rq = 0; rq < 4; ++rq) {
            float4 b = *(const float4*)(eb1 + F0(rq));
            acc[rq * 4 + 0] = b.x; acc[rq * 4 + 1] = b.y;
            acc[rq * 4 + 2] = b.z; acc[rq * 4 + 3] = b.w;
        }
        gemm32<RB128>(pack + OFF_EW1, Ya, lane, cbw, ebk, acc);
#pragma unroll
        for (int rq = 0; rq < 4; ++rq) {
            float s0 = silu(acc[rq * 4 + 0]), s1 = silu(acc[rq * 4 + 1]);
            float s2 = silu(acc[rq * 4 + 2]), s3 = silu(acc[rq * 4 + 3]);
            uint2 u; u.x = f2bf2(s0, s1); u.y = f2bf2(s2, s3);
            *(uint2*)(Yb + e_loc * RB128 + F0(rq) * 2) = u;
        }
    }
    __syncthreads();

    // ---- phase 1.5: segment-reduce Yb into m_i (wave-uniform rows scalarized) ----
    {
        const int rcol = tid & 127;
        const int ch   = tid >> 7;
        float run = 0.f;
        int cur = __builtin_amdgcn_readfirstlane(rowb_s[ch * 16]);
#pragma unroll
        for (int i = 0; i < 16; ++i) {
            int row = ch * 16 + i;
            int rr = __builtin_amdgcn_readfirstlane(rowb_s[row]);
            if (rr != cur) {
                atomicAdd(&m_i[(size_t)cur * HDIM + rcol], run);
                run = 0.f; cur = rr;
            }
            unsigned short u = *(const unsigned short*)(Yb + row * RB128 + rcol * 2);
            run += bf2f(u);
        }
        atomicAdd(&m_i[(size_t)cur * HDIM + rcol], run);
    }

    // ---- phase 2+3 fused: coord hidden in regs, dot with cW1, reduce ----
    {
#pragma unroll
        for (int rq = 0; rq < 4; ++rq) {
            float4 b = *(const float4*)(cb0 + F0(rq));
            acc[rq * 4 + 0] = b.x; acc[rq * 4 + 1] = b.y;
            acc[rq * 4 + 2] = b.z; acc[rq * 4 + 3] = b.w;
        }
        gemm32<RB128>(pack + OFF_CW0, Yb, lane, cbw, ebk, acc);
        float p = 0.f;
#pragma unroll
        for (int rq = 0; rq < 4; ++rq) {
            float4 w1 = *(const float4*)(cW1 + F0(rq));
            p = fmaf(silu(acc[rq * 4 + 0]), w1.x, p);
            p = fmaf(silu(acc[rq * 4 + 1]), w1.y, p);
            p = fmaf(silu(acc[rq * 4 + 2]), w1.z, p);
            p = fmaf(silu(acc[rq * 4 + 3]), w1.w, p);
        }
        p += __shfl_xor(p, 32);
        if (lane < 32) pw[cbw][ebk * 32 + lane] = p;
    }
    __syncthreads();

    if (tid < TME) {
        float s = pw[0][tid] + pw[1][tid] + pw[2][tid] + pw[3][tid];
        float inv = 1.0f / sqrtf(rad_s[tid] + 1e-8f);
        float cwv = s * inv;
        cu_s[tid][0] = dif_s[tid][0] * cwv;
        cu_s[tid][1] = dif_s[tid][1] * cwv;
        cu_s[tid][2] = dif_s[tid][2] * cwv;
    }
    __syncthreads();

    // ---- phase 4: segment-reduce pos updates ----
    if (tid < TME) {
        const int el = tid;
        bool head = (el == 0) || (rowb_s[el] != rowb_s[el - 1]);
        if (head) {
            float sx = 0.f, sy = 0.f, sz = 0.f;
            int r = rowb_s[el];
            int j = el;
            do {
                sx += cu_s[j][0]; sy += cu_s[j][1]; sz += cu_s[j][2];
                ++j;
            } while (j < TME && rowb_s[j] == r);
            atomicAdd(&pos_upd[(size_t)r * 3 + 0], sx);
            atomicAdd(&pos_upd[(size_t)r * 3 + 1], sy);
            atomicAdd(&pos_upd[(size_t)r * 3 + 2], sz);
        }
    }
}

// ---------------- node kernel (m_i-only staging, Hn0-seeded) ----------------
__global__ __launch_bounds__(512)
void egnn_node_kernel(const float* __restrict__ h,
                      const float* __restrict__ pos,
                      const float* __restrict__ m_i,
                      const float* __restrict__ pos_upd,
                      const int*   __restrict__ row_start,
                      const unsigned short* __restrict__ Hn0,
                      const float* __restrict__ nb1,
                      const unsigned short* __restrict__ pack,
                      float* __restrict__ out_h,
                      float* __restrict__ out_pos)
{
    __shared__ __align__(16) char Xs[TMN * RB128];
    __shared__ __align__(16) char Ya[TMN * RB128];

    const int tid = threadIdx.x, lane = tid & 63, cb = tid >> 6;
    const int n0 = blockIdx.x * TMN;

    if (tid < TMN * 3) {
        int nl = tid / 3, d = tid % 3;
        int n = n0 + nl;
        if (n < N_NODES) {
            float dv = (float)(row_start[n + 1] - row_start[n]);
            out_pos[(size_t)n * 3 + d] =
                pos[(size_t)n * 3 + d] + pos_upd[(size_t)n * 3 + d] / (dv + 1e-6f);
        }
    }

    {
        const int nl = tid >> 3, sub = tid & 7, n = n0 + nl;
        if (n < N_NODES) {
            const float4* m4 = (const float4*)(m_i + (size_t)n * HDIM);
#pragma unroll
            for (int q = 0; q < 4; ++q) {
                float4 fm = m4[sub + q * 8];
                uint2 um; um.x = f2bf2(fm.x, fm.y); um.y = f2bf2(fm.z, fm.w);
                *(uint2*)(Xs + nl * RB128 + (sub + q * 8) * 8) = um;
            }
        } else {
            uint2 z{0, 0};
#pragma unroll
            for (int q = 0; q < 4; ++q)
                *(uint2*)(Xs + nl * RB128 + (sub + q * 8) * 8) = z;
        }
    }
    __syncthreads();

    const int j0 = cb * 16 + ((lane >> 4) << 2);
    f32x4 acc[4];

    // GEMM 1: hidden = silu(Hn0 + m_i @ nW0B)
    {
#pragma unroll
        for (int eb = 0; eb < 4; ++eb) {
            int n = n0 + eb * 16 + (lane & 15);
            if (n < N_NODES) {
                uint2 u = *(const uint2*)(Hn0 + (size_t)n * HDIM + j0);
                acc[eb] = f32x4{bflo(u.x), bfhi(u.x), bflo(u.y), bfhi(u.y)};
            } else {
                acc[eb] = f32x4{0.f, 0.f, 0.f, 0.f};
            }
        }
        gemm_layer_T<4, RB128>(pack + OFF_NW0B, Xs, lane, cb, acc);
#pragma unroll
        for (int eb = 0; eb < 4; ++eb) {
            int nl = eb * 16 + (lane & 15);
            float s0 = silu(acc[eb][0]), s1 = silu(acc[eb][1]);
            float s2 = silu(acc[eb][2]), s3 = silu(acc[eb][3]);
            uint2 u; u.x = f2bf2(s0, s1); u.y = f2bf2(s2, s3);
            *(uint2*)(Ya + nl * RB128 + j0 * 2) = u;
        }
    }
    __syncthreads();

    // GEMM 2: out_h = h + hidden @ nW1 + nb1
    {
        float4 b1 = *(const float4*)(nb1 + j0);
#pragma unroll
        for (int eb = 0; eb < 4; ++eb) acc[eb] = f32x4{b1.x, b1.y, b1.z, b1.w};
        gemm_layer_T<4, RB128>(pack + OFF_NW1, Ya, lane, cb, acc);
#pragma unroll
        for (int eb = 0; eb < 4; ++eb) {
            int n = n0 + eb * 16 + (lane & 15);
            if (n < N_NODES) {
                float4 hv = *(const float4*)(h + (size_t)n * HDIM + j0);
                float4 o;
                o.x = hv.x + acc[eb][0]; o.y = hv.y + acc[eb][1];
                o.z = hv.z + acc[eb][2]; o.w = hv.w + acc[eb][3];
                *(float4*)(out_h + (size_t)n * HDIM + j0) = o;
            }
        }
    }
}

extern "C" void kernel_launch(void* const* d_in, const int* in_sizes, int n_in,
                              void* d_out, int out_size, void* d_ws, size_t ws_size,
                              hipStream_t stream) {
    const float* h    = (const float*)d_in[0];
    const float* pos  = (const float*)d_in[1];
    const int*   eidx = (const int*)  d_in[2];
    const float* eW0  = (const float*)d_in[3];
    const float* eb0  = (const float*)d_in[4];
    const float* eW1  = (const float*)d_in[5];
    const float* eb1  = (const float*)d_in[6];
    const float* nW0  = (const float*)d_in[7];
    const float* nb0  = (const float*)d_in[8];
    const float* nW1  = (const float*)d_in[9];
    const float* nb1  = (const float*)d_in[10];
    const float* cW0  = (const float*)d_in[11];
    const float* cb0  = (const float*)d_in[12];
    const float* cW1  = (const float*)d_in[13];

    float* out_h   = (float*)d_out;
    float* out_pos = out_h + (size_t)N_NODES * HDIM;

    // workspace layout
    float* m_i       = (float*)d_ws;                          // N*128 f32  (zeroed)
    float* pos_upd   = m_i + (size_t)N_NODES * HDIM;          // N*3        (zeroed)
    int*   cnt       = (int*)(pos_upd + (size_t)N_NODES * 3); // N          (zeroed)
    int*   row_start = cnt + N_NODES;                         // N+1
    int*   cursor    = row_start + N_NODES + 1;               // N
    int*   bsum      = cursor + N_NODES;                      // 128
    int*   boff      = bsum + 128;                            // 128
    int2*  rc        = (int2*)(boff + 128);                   // E int2
    unsigned short* pack = (unsigned short*)(rc + N_EDGES);
    unsigned short* H0r  = pack + PACK_ELEMS;                 // N*128 bf16
    unsigned short* H0c  = H0r + (size_t)N_NODES * HDIM;      // N*128 bf16
    unsigned short* Hn0  = H0c + (size_t)N_NODES * HDIM;      // N*128 bf16

    size_t zero_bytes = ((size_t)N_NODES * HDIM + (size_t)N_NODES * 3 + N_NODES) * sizeof(float);
    hipMemsetAsync(m_i, 0, zero_bytes, stream);

    pack_weights<<<56, 256, 0, stream>>>(eW0, eW1, cW0, nW0, nW1, pack);

    h0_kernel<<<(N_NODES + TMN - 1) / TMN, 512, 0, stream>>>(
        h, eb0, nb0, pack, eidx, cnt, H0r, H0c, Hn0);

    scanA_kernel<<<SNBLK, 256, 0, stream>>>(cnt, bsum);
    scanB_kernel<<<1, 128, 0, stream>>>(bsum, boff, row_start);
    scanC_kernel<<<SNBLK, 256, 0, stream>>>(cnt, boff, row_start, cursor);
    scatter_kernel<<<(N_EDGES / 4 + 255) / 256, 256, 0, stream>>>(eidx, cursor, rc);

    egnn_edge_kernel<<<N_EDGES / TME, 512, 0, stream>>>(
        H0r, H0c, pos, rc, eW0 + (size_t)256 * HDIM, eb1, cb0, cW1,
        pack, m_i, pos_upd);

    egnn_node_kernel<<<(N_NODES + TMN - 1) / TMN, 512, 0, stream>>>(
        h, pos, m_i, pos_upd, row_start, Hn0, nb1, pack, out_h, out_pos);
}

// Round 11
// 340.285 us; speedup vs baseline: 1.1390x; 1.1390x over previous
//
#include <hip/hip_runtime.h>
#include <hip/hip_bf16.h>
#include <cstddef>

#define N_NODES 50000
#define N_EDGES 800000
#define HDIM    128
#define TME     64
#define TMN     64

// padded LDS row strides (bytes)
#define RB128   272
#define RB256   528

// scan geometry
#define SCHUNK  512
#define SNBLK   ((N_NODES + SCHUNK - 1) / SCHUNK)   // 98

typedef __attribute__((ext_vector_type(4))) float f32x4;
typedef __attribute__((ext_vector_type(8))) short bf16x8;

// pack offsets (bf16 elements)
#define OFF_EW0T 0
#define OFF_EW0B 16384
#define OFF_EW1  32768
#define OFF_CW0  49152
#define OFF_NW0  65536
#define OFF_NW1  98304
#define PACK_ELEMS 114688

__device__ __forceinline__ float silu(float x) {
    float e = __expf(-x);
    return __fdividef(x, 1.0f + e);
}
__device__ __forceinline__ unsigned short f2bf(float f) {
    union { __hip_bfloat16 h; unsigned short u; } cv;
    cv.h = __float2bfloat16(f);
    return cv.u;
}
__device__ __forceinline__ unsigned int f2bf2(float a, float b) {
    union { __hip_bfloat162 h; unsigned int u; } cv;
    cv.h = __float22bfloat162_rn(float2{a, b});
    return cv.u;
}
__device__ __forceinline__ float bf2f(unsigned short u) {
    return __uint_as_float(((unsigned int)u) << 16);
}
__device__ __forceinline__ float bflo(unsigned int u) {
    return __uint_as_float(u << 16);
}
__device__ __forceinline__ float bfhi(unsigned int u) {
    return __uint_as_float(u & 0xffff0000u);
}

// ---------------- weight pack (16x16x32 frag layout, serves A of W^T) ----------------
__global__ void pack_weights(const float* __restrict__ eW0, const float* __restrict__ eW1,
                             const float* __restrict__ cW0, const float* __restrict__ nW0,
                             const float* __restrict__ nW1, unsigned short* __restrict__ pack)
{
    int g = blockIdx.x * blockDim.x + threadIdx.x;   // 0 .. 14335
    int f = g >> 6;
    int lane = g & 63;
    const float* W; int base; int rowoff = 0;
    if (f < 32)       { W = eW0; base = OFF_EW0T; }
    else if (f < 64)  { W = eW0; base = OFF_EW0B; f -= 32; rowoff = 128; }
    else if (f < 96)  { W = eW1; base = OFF_EW1;  f -= 64; }
    else if (f < 128) { W = cW0; base = OFF_CW0;  f -= 96; }
    else if (f < 192) { W = nW0; base = OFF_NW0;  f -= 128; }
    else              { W = nW1; base = OFF_NW1;  f -= 192; }
    int KS = (base == OFF_NW0) ? 8 : 4;
    int cb = f / KS, ks = f % KS;
    int col = cb * 16 + (lane & 15);
    int kbase = rowoff + ks * 32 + ((lane >> 4) << 3);
#pragma unroll
    for (int j = 0; j < 8; ++j)
        pack[(size_t)base + ((size_t)(f * 64 + lane) * 8 + j)] =
            f2bf(W[(size_t)(kbase + j) * HDIM + col]);
}

// ---------------- multi-block scan over cnt[N] ----------------
__global__ __launch_bounds__(256)
void scanA_kernel(const int* __restrict__ cnt, int* __restrict__ bsum) {
    __shared__ int part[256];
    const int b = blockIdx.x, t = threadIdx.x;
    int i0 = b * SCHUNK + t * 2;
    int s = 0;
    if (i0 < N_NODES)     s += cnt[i0];
    if (i0 + 1 < N_NODES) s += cnt[i0 + 1];
    part[t] = s;
    __syncthreads();
    for (int off = 128; off > 0; off >>= 1) {
        if (t < off) part[t] += part[t + off];
        __syncthreads();
    }
    if (t == 0) bsum[b] = part[0];
}

__global__ __launch_bounds__(128)
void scanB_kernel(const int* __restrict__ bsum, int* __restrict__ boff,
                  int* __restrict__ row_start) {
    __shared__ int part[128];
    const int t = threadIdx.x;
    int s = (t < SNBLK) ? bsum[t] : 0;
    part[t] = s;
    __syncthreads();
    for (int off = 1; off < 128; off <<= 1) {
        int tmp = (t >= off) ? part[t - off] : 0;
        __syncthreads();
        part[t] += tmp;
        __syncthreads();
    }
    boff[t] = part[t] - s;           // exclusive
    if (t == 127) row_start[N_NODES] = part[127];
}

__global__ __launch_bounds__(256)
void scanC_kernel(const int* __restrict__ cnt, const int* __restrict__ boff,
                  int* __restrict__ row_start, int* __restrict__ cursor) {
    __shared__ int part[256];
    const int b = blockIdx.x, t = threadIdx.x;
    int i0 = b * SCHUNK + t * 2;
    int c0 = (i0 < N_NODES) ? cnt[i0] : 0;
    int c1 = (i0 + 1 < N_NODES) ? cnt[i0 + 1] : 0;
    int s = c0 + c1;
    part[t] = s;
    __syncthreads();
    for (int off = 1; off < 256; off <<= 1) {
        int tmp = (t >= off) ? part[t - off] : 0;
        __syncthreads();
        part[t] += tmp;
        __syncthreads();
    }
    int base = boff[b] + part[t] - s;
    if (i0 < N_NODES)     { row_start[i0] = base;          cursor[i0] = base; }
    if (i0 + 1 < N_NODES) { row_start[i0 + 1] = base + c0; cursor[i0 + 1] = base + c0; }
}

__global__ void scatter_kernel(const int* __restrict__ eidx, int* __restrict__ cursor,
                               int2* __restrict__ rc) {
    int e = (blockIdx.x * blockDim.x + threadIdx.x) * 4;
    if (e + 3 < N_EDGES) {
        int4 r4 = *(const int4*)(eidx + e);
        int4 c4 = *(const int4*)(eidx + N_EDGES + e);
        int p;
        p = atomicAdd(&cursor[r4.x], 1); rc[p] = int2{r4.x, c4.x};
        p = atomicAdd(&cursor[r4.y], 1); rc[p] = int2{r4.y, c4.y};
        p = atomicAdd(&cursor[r4.z], 1); rc[p] = int2{r4.z, c4.z};
        p = atomicAdd(&cursor[r4.w], 1); rc[p] = int2{r4.w, c4.w};
    } else {
        for (int i = e; i < N_EDGES; ++i) {
            int r = eidx[i], c = eidx[N_EDGES + i];
            int p = atomicAdd(&cursor[r], 1);
            rc[p] = int2{r, c};
        }
    }
}

// ---------------- swapped-operand 16x16x32 GEMM layer ----------------
// Out^T = W^T @ X^T; acc[eb] row = eb*16+(lane&15), feats j0 = cb*16+(lane>>4)*4 .. +3
template<int KS, int ROWB>
__device__ __forceinline__ void gemm_layer_T(const unsigned short* __restrict__ Wseg,
                                             const char* __restrict__ Xs,
                                             int lane, int cb, f32x4 acc[4])
{
    const bf16x8* aptr = (const bf16x8*)Wseg + (size_t)(cb * KS) * 64 + lane;
#pragma unroll
    for (int ks = 0; ks < KS; ++ks) {
        bf16x8 a = aptr[(size_t)ks * 64];
#pragma unroll
        for (int eb = 0; eb < 4; ++eb) {
            int row = eb * 16 + (lane & 15);
            bf16x8 b = *(const bf16x8*)(Xs + row * ROWB + ks * 64 + ((lane >> 4) << 4));
            acc[eb] = __builtin_amdgcn_mfma_f32_16x16x32_bf16(a, b, acc[eb], 0, 0, 0);
        }
    }
}

// ---------------- H0 precompute (+ fused edge histogram) ----------------
__global__ __launch_bounds__(512, 2)
void h0_kernel(const float* __restrict__ h, const float* __restrict__ eb0,
               const unsigned short* __restrict__ pack,
               const int* __restrict__ eidx, int* __restrict__ cnt,
               unsigned short* __restrict__ H0r, unsigned short* __restrict__ H0c)
{
    __shared__ __align__(16) char Xs[TMN * RB128];
    const int tid = threadIdx.x, lane = tid & 63, cb = tid >> 6;
    const int n0 = blockIdx.x * TMN;

    {
        int e = blockIdx.x * 1024 + tid * 2;
        if (e + 1 < N_EDGES) {
            int2 rr = *(const int2*)(eidx + e);
            atomicAdd(&cnt[rr.x], 1);
            atomicAdd(&cnt[rr.y], 1);
        } else if (e < N_EDGES) {
            atomicAdd(&cnt[eidx[e]], 1);
        }
    }

    {
        const int nl = tid >> 3, sub = tid & 7, n = n0 + nl;
        if (n < N_NODES) {
            const float4* h4 = (const float4*)(h + (size_t)n * HDIM);
#pragma unroll
            for (int q = 0; q < 4; ++q) {
                float4 f = h4[sub + q * 8];
                uint2 u; u.x = f2bf2(f.x, f.y); u.y = f2bf2(f.z, f.w);
                *(uint2*)(Xs + nl * RB128 + (sub + q * 8) * 8) = u;
            }
        } else {
            uint2 z{0, 0};
#pragma unroll
            for (int q = 0; q < 4; ++q)
                *(uint2*)(Xs + nl * RB128 + (sub + q * 8) * 8) = z;
        }
    }
    __syncthreads();

    const int j0 = cb * 16 + ((lane >> 4) << 2);
    f32x4 acc[4];
    {
        float4 b0 = *(const float4*)(eb0 + j0);
#pragma unroll
        for (int eb = 0; eb < 4; ++eb) acc[eb] = f32x4{b0.x, b0.y, b0.z, b0.w};
        gemm_layer_T<4, RB128>(pack + OFF_EW0T, Xs, lane, cb, acc);
#pragma unroll
        for (int eb = 0; eb < 4; ++eb) {
            int n = n0 + eb * 16 + (lane & 15);
            if (n < N_NODES) {
                uint2 u; u.x = f2bf2(acc[eb][0], acc[eb][1]); u.y = f2bf2(acc[eb][2], acc[eb][3]);
                *(uint2*)(H0r + (size_t)n * HDIM + j0) = u;
            }
        }
    }
    {
#pragma unroll
        for (int eb = 0; eb < 4; ++eb) acc[eb] = f32x4{0.f, 0.f, 0.f, 0.f};
        gemm_layer_T<4, RB128>(pack + OFF_EW0B, Xs, lane, cb, acc);
#pragma unroll
        for (int eb = 0; eb < 4; ++eb) {
            int n = n0 + eb * 16 + (lane & 15);
            if (n < N_NODES) {
                uint2 u; u.x = f2bf2(acc[eb][0], acc[eb][1]); u.y = f2bf2(acc[eb][2], acc[eb][3]);
                *(uint2*)(H0c + (size_t)n * HDIM + j0) = u;
            }
        }
    }
}

// ---------------- edge kernel (sorted order, XCD-chunked) ----------------
__global__ __launch_bounds__(512, 4)
void egnn_edge_kernel(const unsigned short* __restrict__ H0r,
                      const unsigned short* __restrict__ H0c,
                      const float* __restrict__ pos,
                      const int2*  __restrict__ rc,
                      const float* __restrict__ w256,
                      const float* __restrict__ eb1, const float* __restrict__ cb0,
                      const float* __restrict__ cW1,
                      const unsigned short* __restrict__ pack,
                      float* __restrict__ m_i,
                      float* __restrict__ pos_upd)
{
    __shared__ __align__(16) char Ya[TME * RB128];
    __shared__ __align__(16) char Yb[TME * RB128];
    __shared__ float pw[8][TME];
    __shared__ float rad_s[TME];
    __shared__ float dif_s[TME][3];
    __shared__ float cu_s[TME][4];
    __shared__ int   rowb_s[TME];

    const int tid = threadIdx.x, lane = tid & 63, cb = tid >> 6;

    // bijective XCD-chunked block swizzle
    int lb;
    {
        const int nwg = gridDim.x;
        const int q = nwg >> 3, r = nwg & 7;
        const int xcd = blockIdx.x & 7, idx = blockIdx.x >> 3;
        lb = (xcd < r) ? (xcd * (q + 1) + idx) : (r * (q + 1) + (xcd - r) * q + idx);
    }
    const int e0 = lb * TME;

    // ---- phase 0: gather H0r[row]+H0c[col], radial term, SiLU -> Ya ----
    {
        const int el = tid >> 3, sub = tid & 7, idx = e0 + el;
        const int2 rcv = rc[idx];
        const int r = rcv.x, c = rcv.y;
        float dx = pos[(size_t)r * 3 + 0] - pos[(size_t)c * 3 + 0];
        float dy = pos[(size_t)r * 3 + 1] - pos[(size_t)c * 3 + 1];
        float dz = pos[(size_t)r * 3 + 2] - pos[(size_t)c * 3 + 2];
        float rad = dx * dx + dy * dy + dz * dz;
        if (sub == 0) {
            rad_s[el] = rad;
            dif_s[el][0] = dx; dif_s[el][1] = dy; dif_s[el][2] = dz;
            rowb_s[el] = r;
        }
        const bf16x8* ar = (const bf16x8*)(H0r + (size_t)r * HDIM + sub * 16);
        const bf16x8* ac = (const bf16x8*)(H0c + (size_t)c * HDIM + sub * 16);
        bf16x8 a0 = ar[0], a1 = ar[1];
        bf16x8 c0 = ac[0], c1 = ac[1];
        const float4* wp = (const float4*)(w256 + sub * 16);
        float4 w4[4] = { wp[0], wp[1], wp[2], wp[3] };
        const float* wf = (const float*)w4;
        float v[16];
#pragma unroll
        for (int i = 0; i < 8; ++i) v[i]     = bf2f((unsigned short)a0[i]) + bf2f((unsigned short)c0[i]);
#pragma unroll
        for (int i = 0; i < 8; ++i) v[8 + i] = bf2f((unsigned short)a1[i]) + bf2f((unsigned short)c1[i]);
#pragma unroll
        for (int i = 0; i < 16; ++i) v[i] = silu(fmaf(rad, wf[i], v[i]));
#pragma unroll
        for (int c4 = 0; c4 < 4; ++c4) {
            uint2 u;
            u.x = f2bf2(v[c4 * 4 + 0], v[c4 * 4 + 1]);
            u.y = f2bf2(v[c4 * 4 + 2], v[c4 * 4 + 3]);
            *(uint2*)(Ya + el * RB128 + sub * 32 + c4 * 8) = u;
        }
    }
    __syncthreads();

    const int j0 = cb * 16 + ((lane >> 4) << 2);
    f32x4 acc[4];

    // ---- phase 1: m_ij = silu(Ya @ eW1 + eb1) -> Yb (vectorized b64 writes) ----
    {
        float4 b1 = *(const float4*)(eb1 + j0);
#pragma unroll
        for (int eb = 0; eb < 4; ++eb) acc[eb] = f32x4{b1.x, b1.y, b1.z, b1.w};
        gemm_layer_T<4, RB128>(pack + OFF_EW1, Ya, lane, cb, acc);
#pragma unroll
        for (int eb = 0; eb < 4; ++eb) {
            int e = eb * 16 + (lane & 15);
            float s0 = silu(acc[eb][0]), s1 = silu(acc[eb][1]);
            float s2 = silu(acc[eb][2]), s3 = silu(acc[eb][3]);
            uint2 u; u.x = f2bf2(s0, s1); u.y = f2bf2(s2, s3);
            *(uint2*)(Yb + e * RB128 + j0 * 2) = u;
        }
    }
    __syncthreads();

    // ---- phase 1.5: segment-reduce Yb into m_i (wave-uniform rows scalarized) ----
    {
        const int rcol = tid & 127;
        const int ch   = tid >> 7;
        float run = 0.f;
        int cur = __builtin_amdgcn_readfirstlane(rowb_s[ch * 16]);
#pragma unroll
        for (int i = 0; i < 16; ++i) {
            int row = ch * 16 + i;
            int rr = __builtin_amdgcn_readfirstlane(rowb_s[row]);
            if (rr != cur) {
                atomicAdd(&m_i[(size_t)cur * HDIM + rcol], run);
                run = 0.f; cur = rr;
            }
            unsigned short u = *(const unsigned short*)(Yb + row * RB128 + rcol * 2);
            run += bf2f(u);
        }
        atomicAdd(&m_i[(size_t)cur * HDIM + rcol], run);
    }

    // ---- phase 2+3 fused: coord hidden in regs, dot with cW1, cross-wave reduce ----
    {
        float4 b2 = *(const float4*)(cb0 + j0);
#pragma unroll
        for (int eb = 0; eb < 4; ++eb) acc[eb] = f32x4{b2.x, b2.y, b2.z, b2.w};
        gemm_layer_T<4, RB128>(pack + OFF_CW0, Yb, lane, cb, acc);
        float4 w1 = *(const float4*)(cW1 + j0);
        float pe[4];
#pragma unroll
        for (int eb = 0; eb < 4; ++eb) {
            float p;
            p = silu(acc[eb][0]) * w1.x;
            p = fmaf(silu(acc[eb][1]), w1.y, p);
            p = fmaf(silu(acc[eb][2]), w1.z, p);
            p = fmaf(silu(acc[eb][3]), w1.w, p);
            p += __shfl_xor(p, 16);
            p += __shfl_xor(p, 32);
            pe[eb] = p;
        }
        if (lane < 16) {
#pragma unroll
            for (int eb = 0; eb < 4; ++eb) pw[cb][eb * 16 + lane] = pe[eb];
        }
    }
    __syncthreads();

    if (tid < TME) {
        float s = 0.f;
#pragma unroll
        for (int w = 0; w < 8; ++w) s += pw[w][tid];
        float inv = 1.0f / sqrtf(rad_s[tid] + 1e-8f);
        float cwv = s * inv;
        cu_s[tid][0] = dif_s[tid][0] * cwv;
        cu_s[tid][1] = dif_s[tid][1] * cwv;
        cu_s[tid][2] = dif_s[tid][2] * cwv;
    }
    __syncthreads();

    // ---- phase 4: segment-reduce pos updates ----
    if (tid < TME) {
        const int el = tid;
        bool head = (el == 0) || (rowb_s[el] != rowb_s[el - 1]);
        if (head) {
            float sx = 0.f, sy = 0.f, sz = 0.f;
            int r = rowb_s[el];
            int j = el;
            do {
                sx += cu_s[j][0]; sy += cu_s[j][1]; sz += cu_s[j][2];
                ++j;
            } while (j < TME && rowb_s[j] == r);
            atomicAdd(&pos_upd[(size_t)r * 3 + 0], sx);
            atomicAdd(&pos_upd[(size_t)r * 3 + 1], sy);
            atomicAdd(&pos_upd[(size_t)r * 3 + 2], sz);
        }
    }
}

// ---------------- node kernel ----------------
__global__ __launch_bounds__(512)
void egnn_node_kernel(const float* __restrict__ h,
                      const float* __restrict__ pos,
                      const float* __restrict__ m_i,
                      const float* __restrict__ pos_upd,
                      const int*   __restrict__ row_start,
                      const float* __restrict__ nb0, const float* __restrict__ nb1,
                      const unsigned short* __restrict__ pack,
                      float* __restrict__ out_h,
                      float* __restrict__ out_pos)
{
    __shared__ __align__(16) char Xs[TMN * RB256];
    __shared__ __align__(16) char Ya[TMN * RB128];

    const int tid = threadIdx.x, lane = tid & 63, cb = tid >> 6;
    const int n0 = blockIdx.x * TMN;

    if (tid < TMN * 3) {
        int nl = tid / 3, d = tid % 3;
        int n = n0 + nl;
        if (n < N_NODES) {
            float dv = (float)(row_start[n + 1] - row_start[n]);
            out_pos[(size_t)n * 3 + d] =
                pos[(size_t)n * 3 + d] + pos_upd[(size_t)n * 3 + d] / (dv + 1e-6f);
        }
    }

    {
        const int nl = tid >> 3, sub = tid & 7, n = n0 + nl;
        if (n < N_NODES) {
            const float4* h4 = (const float4*)(h   + (size_t)n * HDIM);
            const float4* m4 = (const float4*)(m_i + (size_t)n * HDIM);
#pragma unroll
            for (int q = 0; q < 4; ++q) {
                float4 fh = h4[sub + q * 8];
                float4 fm = m4[sub + q * 8];
                uint2 uh; uh.x = f2bf2(fh.x, fh.y); uh.y = f2bf2(fh.z, fh.w);
                uint2 um; um.x = f2bf2(fm.x, fm.y); um.y = f2bf2(fm.z, fm.w);
                *(uint2*)(Xs + nl * RB256 + (sub + q * 8) * 8)       = uh;
                *(uint2*)(Xs + nl * RB256 + 256 + (sub + q * 8) * 8) = um;
            }
        } else {
            uint2 z{0, 0};
#pragma unroll
            for (int q = 0; q < 4; ++q) {
                *(uint2*)(Xs + nl * RB256 + (sub + q * 8) * 8)       = z;
                *(uint2*)(Xs + nl * RB256 + 256 + (sub + q * 8) * 8) = z;
            }
        }
    }
    __syncthreads();

    const int j0 = cb * 16 + ((lane >> 4) << 2);
    f32x4 acc[4];

    {
        float4 b0 = *(const float4*)(nb0 + j0);
#pragma unroll
        for (int eb = 0; eb < 4; ++eb) acc[eb] = f32x4{b0.x, b0.y, b0.z, b0.w};
        gemm_layer_T<8, RB256>(pack + OFF_NW0, Xs, lane, cb, acc);
#pragma unroll
        for (int eb = 0; eb < 4; ++eb) {
            int nl = eb * 16 + (lane & 15);
            float s0 = silu(acc[eb][0]), s1 = silu(acc[eb][1]);
            float s2 = silu(acc[eb][2]), s3 = silu(acc[eb][3]);
            uint2 u; u.x = f2bf2(s0, s1); u.y = f2bf2(s2, s3);
            *(uint2*)(Ya + nl * RB128 + j0 * 2) = u;
        }
    }
    __syncthreads();

    {
        float4 b1 = *(const float4*)(nb1 + j0);
#pragma unroll
        for (int eb = 0; eb < 4; ++eb) acc[eb] = f32x4{b1.x, b1.y, b1.z, b1.w};
        gemm_layer_T<4, RB128>(pack + OFF_NW1, Ya, lane, cb, acc);
#pragma unroll
        for (int eb = 0; eb < 4; ++eb) {
            int n = n0 + eb * 16 + (lane & 15);
            if (n < N_NODES) {
                float4 hv = *(const float4*)(h + (size_t)n * HDIM + j0);
                float4 o;
                o.x = hv.x + acc[eb][0]; o.y = hv.y + acc[eb][1];
                o.z = hv.z + acc[eb][2]; o.w = hv.w + acc[eb][3];
                *(float4*)(out_h + (size_t)n * HDIM + j0) = o;
            }
        }
    }
}

extern "C" void kernel_launch(void* const* d_in, const int* in_sizes, int n_in,
                              void* d_out, int out_size, void* d_ws, size_t ws_size,
                              hipStream_t stream) {
    const float* h    = (const float*)d_in[0];
    const float* pos  = (const float*)d_in[1];
    const int*   eidx = (const int*)  d_in[2];
    const float* eW0  = (const float*)d_in[3];
    const float* eb0  = (const float*)d_in[4];
    const float* eW1  = (const float*)d_in[5];
    const float* eb1  = (const float*)d_in[6];
    const float* nW0  = (const float*)d_in[7];
    const float* nb0  = (const float*)d_in[8];
    const float* nW1  = (const float*)d_in[9];
    const float* nb1  = (const float*)d_in[10];
    const float* cW0  = (const float*)d_in[11];
    const float* cb0  = (const float*)d_in[12];
    const float* cW1  = (const float*)d_in[13];

    float* out_h   = (float*)d_out;
    float* out_pos = out_h + (size_t)N_NODES * HDIM;

    // workspace layout
    float* m_i       = (float*)d_ws;                          // N*128 f32  (zeroed)
    float* pos_upd   = m_i + (size_t)N_NODES * HDIM;          // N*3        (zeroed)
    int*   cnt       = (int*)(pos_upd + (size_t)N_NODES * 3); // N          (zeroed)
    int*   row_start = cnt + N_NODES;                         // N+1
    int*   cursor    = row_start + N_NODES + 1;               // N
    int*   bsum      = cursor + N_NODES;                      // 128
    int*   boff      = bsum + 128;                            // 128
    int2*  rc        = (int2*)(boff + 128);                   // E int2
    unsigned short* pack = (unsigned short*)(rc + N_EDGES);
    unsigned short* H0r  = pack + PACK_ELEMS;                 // N*128 bf16
    unsigned short* H0c  = H0r + (size_t)N_NODES * HDIM;      // N*128 bf16

    size_t zero_bytes = ((size_t)N_NODES * HDIM + (size_t)N_NODES * 3 + N_NODES) * sizeof(float);
    hipMemsetAsync(m_i, 0, zero_bytes, stream);

    pack_weights<<<56, 256, 0, stream>>>(eW0, eW1, cW0, nW0, nW1, pack);

    h0_kernel<<<(N_NODES + TMN - 1) / TMN, 512, 0, stream>>>(h, eb0, pack, eidx, cnt, H0r, H0c);

    scanA_kernel<<<SNBLK, 256, 0, stream>>>(cnt, bsum);
    scanB_kernel<<<1, 128, 0, stream>>>(bsum, boff, row_start);
    scanC_kernel<<<SNBLK, 256, 0, stream>>>(cnt, boff, row_start, cursor);
    scatter_kernel<<<(N_EDGES / 4 + 255) / 256, 256, 0, stream>>>(eidx, cursor, rc);

    egnn_edge_kernel<<<N_EDGES / TME, 512, 0, stream>>>(
        H0r, H0c, pos, rc, eW0 + (size_t)256 * HDIM, eb1, cb0, cW1,
        pack, m_i, pos_upd);

    egnn_node_kernel<<<(N_NODES + TMN - 1) / TMN, 512, 0, stream>>>(
        h, pos, m_i, pos_upd, row_start, nb0, nb1, pack, out_h, out_pos);
}